// Round 4
// baseline (341.077 us; speedup 1.0000x reference)
//
#include <hip/hip_runtime.h>
#include <hip/hip_bf16.h>

#define NSTEPS 730
#define NGRID  10000
#define LENF   15
#define NEARZERO 1e-5f

// fast pow(x, e) for x > 0 via v_log_f32 / v_exp_f32 (both base-2)
__device__ __forceinline__ float fast_pow(float x, float e) {
    return __builtin_amdgcn_exp2f(e * __builtin_amdgcn_logf(x));
}

struct HbvParams {
    float TT, CFMAX, CFRxCFMAX, CWH;
    float FC, invFC, BETA, invLPFC, BETAET, C;
    float PERC, K0, K1, K2, UZL;
};

struct HbvState {
    float snow, melt, sm, suz, slz;
};

// One HBV time step. Returns q = q0+q1+q2.
__device__ __forceinline__ float hbv_step(float p, float tmn, float pet,
                                          HbvState& s, const HbvParams& P) {
    // snow routine
    float rain     = (tmn >= P.TT) ? p : 0.0f;
    float snowfall = p - rain;
    s.snow += snowfall;
    float m = fminf(fmaxf(P.CFMAX * (tmn - P.TT), 0.0f), s.snow);
    s.melt += m; s.snow -= m;
    float refr = fminf(fmaxf(P.CFRxCFMAX * (P.TT - tmn), 0.0f), s.melt);
    s.snow += refr; s.melt -= refr;
    float tosoil = fmaxf(s.melt - P.CWH * s.snow, 0.0f);
    s.melt -= tosoil;

    // soil routine
    float soil_wet = fminf(fast_pow(s.sm * P.invFC, P.BETA), 1.0f);
    float rt_in    = rain + tosoil;
    float recharge = rt_in * soil_wet;
    s.sm += rt_in - recharge;
    float excess = fmaxf(s.sm - P.FC, 0.0f);
    s.sm -= excess;
    float evapfac = fminf(fast_pow(s.sm * P.invLPFC, P.BETAET), 1.0f);
    float etact   = fminf(s.sm, pet * evapfac);
    s.sm = fmaxf(s.sm - etact, NEARZERO);
    float capillary = fminf(s.slz, P.C * s.slz * (1.0f - fminf(s.sm * P.invFC, 1.0f)));
    s.sm  = fmaxf(s.sm + capillary, NEARZERO);
    s.slz = fmaxf(s.slz - capillary, NEARZERO);

    // runoff
    s.suz += recharge + excess;
    float percact = fminf(s.suz, P.PERC);
    s.suz -= percact;
    float q0 = P.K0 * fmaxf(s.suz - P.UZL, 0.0f);
    s.suz -= q0;
    float q1 = P.K1 * s.suz;
    s.suz -= q1;
    s.slz += percact;
    float q2 = P.K2 * s.slz;
    s.slz -= q2;
    return q0 + q1 + q2;
}

// Fully fused: per-cell sequential HBV chain + in-register 15-tap gamma routing.
// One thread per grid cell. FP32 inputs/outputs (reference dtype). No workspace.
// Time loop unrolled by 15 -> static circular q-history indices; depth-15
// register prefetch of (p, t, pet).
__global__ __launch_bounds__(64) void hbv_fused(const float* __restrict__ xp,
                                                const float* __restrict__ ps,
                                                float* __restrict__ out) {
    int g = blockIdx.x * 64 + threadIdx.x;
    if (g >= NGRID) return;

    // --- parameters (raw in [0,1], scaled per PARAM_BOUNDS) ---
    const int pb = g * 16;
    HbvParams P;
    {
        float rBETA   = ps[pb + 0];
        float rFC     = ps[pb + 1];
        float rK0     = ps[pb + 2];
        float rK1     = ps[pb + 3];
        float rK2     = ps[pb + 4];
        float rLP     = ps[pb + 5];
        float rPERC   = ps[pb + 6];
        float rUZL    = ps[pb + 7];
        float rTT     = ps[pb + 8];
        float rCFMAX  = ps[pb + 9];
        float rCFR    = ps[pb + 10];
        float rCWH    = ps[pb + 11];
        float rBETAET = ps[pb + 12];
        float rC      = ps[pb + 13];

        P.BETA   = rBETA   * 5.0f   + 1.0f;
        P.FC     = rFC     * 950.0f + 50.0f;
        P.K0     = rK0     * 0.85f  + 0.05f;
        P.K1     = rK1     * 0.49f  + 0.01f;
        P.K2     = rK2     * 0.199f + 0.001f;
        float LP = rLP     * 0.8f   + 0.2f;
        P.PERC   = rPERC   * 10.0f;
        P.UZL    = rUZL    * 100.0f;
        P.TT     = rTT     * 5.0f   - 2.5f;
        float CFMAX = rCFMAX * 9.5f + 0.5f;
        P.CFMAX  = CFMAX;
        P.CFRxCFMAX = (rCFR * 0.1f) * CFMAX;
        P.CWH    = rCWH    * 0.2f;
        P.BETAET = rBETAET * 4.7f   + 0.3f;
        P.C      = rC;
        P.invFC   = 1.0f / P.FC;
        P.invLPFC = 1.0f / (LP * P.FC);
    }

    // --- routing weights. -lgamma(aa) - aa*log(theta) are k-independent and
    // cancel under normalization -> dropped. Base-2:
    // lw2 = (aa-1)*log2(tg) - (tg/theta)*log2(e)
    float w[LENF];
    {
        const float LOG2E = 1.4426950408889634f;
        float aa       = fmaxf(ps[pb + 14] * 2.9f, 0.0f) + 0.1f;
        float theta    = fmaxf(ps[pb + 15] * 6.5f, 0.0f) + 0.5f;
        float s        = LOG2E / theta;
        float am1 = aa - 1.0f;
        float wsum = 0.0f;
#pragma unroll
        for (int k = 0; k < LENF; ++k) {
            float tg = (float)k + 0.5f;
            w[k] = __builtin_amdgcn_exp2f(am1 * __builtin_amdgcn_logf(tg) - tg * s);
            wsum += w[k];
        }
        float inv = 1.0f / wsum;
#pragma unroll
        for (int k = 0; k < LENF; ++k) w[k] *= inv;
    }

    // --- state + circular q-history (zero-init == reference zero padding) ---
    HbvState st{NEARZERO, NEARZERO, NEARZERO, NEARZERO, NEARZERO};
    float qh[LENF];
#pragma unroll
    for (int k = 0; k < LENF; ++k) qh[k] = 0.0f;

    // --- depth-15 register prefetch of (p, t, pet) ---
    float rp[LENF], rt[LENF], re[LENF];
#pragma unroll
    for (int i = 0; i < LENF; ++i) {
        int idx = (i * NGRID + g) * 3;
        rp[i] = xp[idx]; rt[i] = xp[idx + 1]; re[i] = xp[idx + 2];
    }

    // main loop: 48 full blocks of 15 steps (720), then 10-step tail
    for (int tb = 0; tb < 720; tb += LENF) {
#pragma unroll
        for (int i = 0; i < LENF; ++i) {
            int t = tb + i;
            float p   = rp[i];
            float tmn = rt[i];
            float pet = re[i];
            int tn = t + LENF;
            if (tn < NSTEPS) {
                int idx = (tn * NGRID + g) * 3;
                rp[i] = xp[idx]; rt[i] = xp[idx + 1]; re[i] = xp[idx + 2];
            }

            float q = hbv_step(p, tmn, pet, st, P);
            qh[i] = q;                       // phase = i (tb % 15 == 0)
            float acc = 0.0f;
#pragma unroll
            for (int k = 0; k < LENF; ++k)
                acc = fmaf(w[k], qh[(i - k + LENF) % LENF], acc);
            out[t * NGRID + g] = acc;
        }
    }
#pragma unroll
    for (int i = 0; i < 10; ++i) {           // t = 720..729, phase 0..9
        int t = 720 + i;
        float q = hbv_step(rp[i], rt[i], re[i], st, P);
        qh[i] = q;
        float acc = 0.0f;
#pragma unroll
        for (int k = 0; k < LENF; ++k)
            acc = fmaf(w[k], qh[(i - k + LENF) % LENF], acc);
        out[t * NGRID + g] = acc;
    }
}

extern "C" void kernel_launch(void* const* d_in, const int* in_sizes, int n_in,
                              void* d_out, int out_size, void* d_ws, size_t ws_size,
                              hipStream_t stream) {
    const float* x_phy      = (const float*)d_in[0]; // f32 (730,10000,3)
    const float* phy_static = (const float*)d_in[1]; // f32 (10000,16)
    float* out = (float*)d_out;                      // f32 (730,10000)

    hbv_fused<<<(NGRID + 63) / 64, 64, 0, stream>>>(x_phy, phy_static, out);
}

// Round 5
// 304.825 us; speedup vs baseline: 1.1189x; 1.1189x over previous
//
#include <hip/hip_runtime.h>

#define NSTEPS 730
#define NGRID  10000
#define LENF   15
#define NEARZERO 1e-5f
#define PF 5   // prefetch depth; must divide LENF so slot indices stay static

// fast pow(x, e) for x > 0 via v_log_f32 / v_exp_f32 (both base-2)
__device__ __forceinline__ float fast_pow(float x, float e) {
    return __builtin_amdgcn_exp2f(e * __builtin_amdgcn_logf(x));
}

struct F3 { float p, t, e; };  // one (prcp, tmean, pet) sample; 12B, dword-aligned

struct HbvParams {
    float TT, CFMAX, CFRxCFMAX, CWH;
    float FC, invFC, BETA, invLPFC, BETAET, C;
    float PERC, K0, K1, K2, UZL;
};

struct HbvState {
    float snow, melt, sm, suz, slz;
};

// One HBV time step. Returns q = q0+q1+q2.
__device__ __forceinline__ float hbv_step(float p, float tmn, float pet,
                                          HbvState& s, const HbvParams& P) {
    // snow routine
    float rain     = (tmn >= P.TT) ? p : 0.0f;
    float snowfall = p - rain;
    s.snow += snowfall;
    float m = fminf(fmaxf(P.CFMAX * (tmn - P.TT), 0.0f), s.snow);
    s.melt += m; s.snow -= m;
    float refr = fminf(fmaxf(P.CFRxCFMAX * (P.TT - tmn), 0.0f), s.melt);
    s.snow += refr; s.melt -= refr;
    float tosoil = fmaxf(s.melt - P.CWH * s.snow, 0.0f);
    s.melt -= tosoil;

    // soil routine
    float soil_wet = fminf(fast_pow(s.sm * P.invFC, P.BETA), 1.0f);
    float rt_in    = rain + tosoil;
    float recharge = rt_in * soil_wet;
    s.sm += rt_in - recharge;
    float excess = fmaxf(s.sm - P.FC, 0.0f);
    s.sm -= excess;
    float evapfac = fminf(fast_pow(s.sm * P.invLPFC, P.BETAET), 1.0f);
    float etact   = fminf(s.sm, pet * evapfac);
    s.sm = fmaxf(s.sm - etact, NEARZERO);
    float capillary = fminf(s.slz, P.C * s.slz * (1.0f - fminf(s.sm * P.invFC, 1.0f)));
    s.sm  = fmaxf(s.sm + capillary, NEARZERO);
    s.slz = fmaxf(s.slz - capillary, NEARZERO);

    // runoff
    s.suz += recharge + excess;
    float percact = fminf(s.suz, P.PERC);
    s.suz -= percact;
    float q0 = P.K0 * fmaxf(s.suz - P.UZL, 0.0f);
    s.suz -= q0;
    float q1 = P.K1 * s.suz;
    s.suz -= q1;
    s.slz += percact;
    float q2 = P.K2 * s.slz;
    s.slz -= q2;
    return q0 + q1 + q2;
}

// Fully fused: per-cell sequential HBV chain + in-register 15-tap gamma routing.
// One thread per grid cell, fp32 in/out, no workspace.
// __launch_bounds__(64,1): 1 wave/SIMD is all the parallelism this problem has,
// so give the register allocator the full budget -> no scratch spills.
__global__ __launch_bounds__(64, 1) void hbv_fused(const float* __restrict__ xp,
                                                   const float* __restrict__ ps,
                                                   float* __restrict__ out) {
    int g = blockIdx.x * 64 + threadIdx.x;
    if (g >= NGRID) return;

    // --- parameters (raw in [0,1], scaled per PARAM_BOUNDS) ---
    const int pb = g * 16;
    HbvParams P;
    {
        P.BETA   = ps[pb + 0]  * 5.0f   + 1.0f;
        P.FC     = ps[pb + 1]  * 950.0f + 50.0f;
        P.K0     = ps[pb + 2]  * 0.85f  + 0.05f;
        P.K1     = ps[pb + 3]  * 0.49f  + 0.01f;
        P.K2     = ps[pb + 4]  * 0.199f + 0.001f;
        float LP = ps[pb + 5]  * 0.8f   + 0.2f;
        P.PERC   = ps[pb + 6]  * 10.0f;
        P.UZL    = ps[pb + 7]  * 100.0f;
        P.TT     = ps[pb + 8]  * 5.0f   - 2.5f;
        float CFMAX = ps[pb + 9] * 9.5f + 0.5f;
        P.CFMAX  = CFMAX;
        P.CFRxCFMAX = (ps[pb + 10] * 0.1f) * CFMAX;
        P.CWH    = ps[pb + 11] * 0.2f;
        P.BETAET = ps[pb + 12] * 4.7f   + 0.3f;
        P.C      = ps[pb + 13];
        P.invFC   = 1.0f / P.FC;
        P.invLPFC = 1.0f / (LP * P.FC);
    }

    // --- routing weights. -lgamma(aa) - aa*log(theta) are k-independent and
    // cancel under normalization -> dropped.
    // Base-2: lw2 = (aa-1)*log2(tg) - (tg/theta)*log2(e)
    float w[LENF];
    {
        const float LOG2E = 1.4426950408889634f;
        float aa    = fmaxf(ps[pb + 14] * 2.9f, 0.0f) + 0.1f;
        float theta = fmaxf(ps[pb + 15] * 6.5f, 0.0f) + 0.5f;
        float sc    = LOG2E / theta;
        float am1   = aa - 1.0f;
        float wsum = 0.0f;
#pragma unroll
        for (int k = 0; k < LENF; ++k) {
            float tg = (float)k + 0.5f;
            w[k] = __builtin_amdgcn_exp2f(am1 * __builtin_amdgcn_logf(tg) - tg * sc);
            wsum += w[k];
        }
        float inv = 1.0f / wsum;
#pragma unroll
        for (int k = 0; k < LENF; ++k) w[k] *= inv;
    }

    // --- state + circular q-history (zero-init == reference zero padding) ---
    HbvState st{NEARZERO, NEARZERO, NEARZERO, NEARZERO, NEARZERO};
    float qh[LENF];
#pragma unroll
    for (int k = 0; k < LENF; ++k) qh[k] = 0.0f;

    // --- depth-PF vectorized prefetch of (p, t, pet): one dwordx3 per step ---
    const F3* __restrict__ xv = (const F3*)xp;
    F3 pf[PF];
#pragma unroll
    for (int i = 0; i < PF; ++i) pf[i] = xv[(size_t)i * NGRID + g];

    // main loop: 48 blocks of 15 steps (t = 0..719). Prefetch t+PF <= 724 < 730,
    // so no guard needed here.
    for (int tb = 0; tb < 720; tb += LENF) {
#pragma unroll
        for (int i = 0; i < LENF; ++i) {
            int t = tb + i;
            F3 cur = pf[i % PF];
            pf[i % PF] = xv[(size_t)(t + PF) * NGRID + g];

            float q = hbv_step(cur.p, cur.t, cur.e, st, P);
            qh[i] = q;                         // phase = i (tb % 15 == 0)
            float acc = 0.0f;
#pragma unroll
            for (int k = 0; k < LENF; ++k)
                acc = fmaf(w[k], qh[(i - k + LENF) % LENF], acc);
            out[t * NGRID + g] = acc;
        }
    }

    // tail: t = 720..729 (phase 0..9); prefetch only while t+PF < 730
#pragma unroll
    for (int i = 0; i < 10; ++i) {
        int t = 720 + i;
        F3 cur = pf[i % PF];
        if (i < PF)
            pf[i % PF] = xv[(size_t)(t + PF) * NGRID + g];

        float q = hbv_step(cur.p, cur.t, cur.e, st, P);
        qh[i] = q;
        float acc = 0.0f;
#pragma unroll
        for (int k = 0; k < LENF; ++k)
            acc = fmaf(w[k], qh[(i - k + LENF) % LENF], acc);
        out[t * NGRID + g] = acc;
    }
}

extern "C" void kernel_launch(void* const* d_in, const int* in_sizes, int n_in,
                              void* d_out, int out_size, void* d_ws, size_t ws_size,
                              hipStream_t stream) {
    const float* x_phy      = (const float*)d_in[0]; // f32 (730,10000,3)
    const float* phy_static = (const float*)d_in[1]; // f32 (10000,16)
    float* out = (float*)d_out;                      // f32 (730,10000)

    hbv_fused<<<(NGRID + 63) / 64, 64, 0, stream>>>(x_phy, phy_static, out);
}